// Round 1
// baseline (1996.018 us; speedup 1.0000x reference)
//
#include <hip/hip_runtime.h>
#include <math.h>

// FrameletLayer: Chebyshev framelet graph conv + complex linear + CSiLU.
// C=128 channels, K=6, F=4, S=1.0. Real+imag fused as [N, 256] rows.

#define CH   128
#define CH2  256

// ---------------- CSR build ----------------

__global__ void zero_counts_k(int* cnt, int n) {
    int i = blockIdx.x * blockDim.x + threadIdx.x;
    if (i < n) cnt[i] = 0;
}

__global__ void hist_k(const int* __restrict__ row, int* cnt, int E) {
    int e = blockIdx.x * blockDim.x + threadIdx.x;
    if (e < E) atomicAdd(&cnt[row[e]], 1);
}

// chunk = 1024 elements per block (256 threads x 4)
__global__ void scan_partial_k(const int* __restrict__ cnt, int* partials, int N) {
    __shared__ int sd[256];
    int t = threadIdx.x;
    int base = blockIdx.x * 1024;
    int s = 0;
    #pragma unroll
    for (int j = 0; j < 4; j++) {
        int i = base + t * 4 + j;
        if (i < N) s += cnt[i];
    }
    sd[t] = s;
    __syncthreads();
    for (int off = 128; off > 0; off >>= 1) {
        if (t < off) sd[t] += sd[t + off];
        __syncthreads();
    }
    if (t == 0) partials[blockIdx.x] = sd[0];
}

__global__ void scan_toplevel_k(const int* __restrict__ partials, int* poff, int nb) {
    if (threadIdx.x == 0 && blockIdx.x == 0) {
        int run = 0;
        for (int b = 0; b < nb; b++) { poff[b] = run; run += partials[b]; }
    }
}

__global__ void scan_write_k(const int* __restrict__ cnt, const int* __restrict__ poff,
                             int* row_start, int* edge_pos, int N, int E) {
    __shared__ int sd[256];
    int t = threadIdx.x;
    int base = blockIdx.x * 1024;
    int v[4];
    int s = 0;
    #pragma unroll
    for (int j = 0; j < 4; j++) {
        int i = base + t * 4 + j;
        v[j] = (i < N) ? cnt[i] : 0;
        s += v[j];
    }
    sd[t] = s;
    __syncthreads();
    // Hillis-Steele inclusive scan over 256 thread sums
    for (int off = 1; off < 256; off <<= 1) {
        int y = (t >= off) ? sd[t - off] : 0;
        __syncthreads();
        sd[t] += y;
        __syncthreads();
    }
    int run = poff[blockIdx.x] + ((t == 0) ? 0 : sd[t - 1]);
    #pragma unroll
    for (int j = 0; j < 4; j++) {
        int i = base + t * 4 + j;
        if (i < N) { row_start[i] = run; edge_pos[i] = run; run += v[j]; }
    }
    if (blockIdx.x == 0 && t == 0) row_start[N] = E;
}

__global__ void scatter_k(const int* __restrict__ row, const int* __restrict__ col,
                          const float* __restrict__ w, int* edge_pos,
                          int* csr_col, float* csr_w, int E) {
    int e = blockIdx.x * blockDim.x + threadIdx.x;
    if (e < E) {
        int r = row[e];
        int p = atomicAdd(&edge_pos[r], 1);
        csr_col[p] = col[e];
        csr_w[p]   = -w[e];   // store B = -A/S (S = 1.0)
    }
}

// c[k] = sum_f theta[f] * approx[f][k]
__global__ void coef_k(const float* __restrict__ approx, const float* __restrict__ theta,
                       float* c) {
    int k = threadIdx.x;
    if (k < 6 && blockIdx.x == 0) {
        float s = 0.f;
        for (int f = 0; f < 4; f++) s += theta[f] * approx[f * 6 + k];
        c[k] = s;
    }
}

// ---------------- SpMM steps ----------------
// T1 = B*x ; acc = c0*x + c1*T1   (acc lives in d_out, layout [2][N][CH])
__global__ __launch_bounds__(256) void spmm_first_k(
        const float* __restrict__ xr, const float* __restrict__ xi,
        const int* __restrict__ row_start, const int* __restrict__ csr_col,
        const float* __restrict__ csr_w, const float* __restrict__ c,
        float* __restrict__ t1buf, float* __restrict__ acc, int N) {
    int i = blockIdx.x;
    int t = threadIdx.x;
    int beg = row_start[i], end = row_start[i + 1];
    bool isReal = t < CH;
    int ch = t & (CH - 1);
    const float* src = isReal ? xr : xi;
    float sum = 0.f;
    for (int e = beg; e < end; e++) {
        int cc = csr_col[e];
        float wv = csr_w[e];
        sum += wv * src[(size_t)cc * CH + ch];
    }
    t1buf[(size_t)i * CH2 + t] = sum;
    float own = src[(size_t)i * CH + ch];
    float a = c[0] * own + c[1] * sum;
    acc[(size_t)(isReal ? 0 : 1) * N * CH + (size_t)i * CH + ch] = a;
}

// T2 = 2*B*cur - prev ; acc += c[k]*T2 ; dst may alias prev (own-row only)
__global__ __launch_bounds__(256) void spmm_step_k(
        const float* __restrict__ cur,
        const float* __restrict__ prevA, const float* __restrict__ prevB, // prevB!=null => prev is (xr,xi) inputs
        const int* __restrict__ row_start, const int* __restrict__ csr_col,
        const float* __restrict__ csr_w, const float* __restrict__ c, int k,
        float* __restrict__ dst, float* __restrict__ acc, int N) {
    int i = blockIdx.x;
    int t = threadIdx.x;
    int beg = row_start[i], end = row_start[i + 1];
    float sum = 0.f;
    for (int e = beg; e < end; e++) {
        int cc = csr_col[e];
        float wv = csr_w[e];
        sum += wv * cur[(size_t)cc * CH2 + t];
    }
    bool isReal = t < CH;
    int ch = t & (CH - 1);
    float prev;
    if (prevB != nullptr) {
        prev = (isReal ? prevA : prevB)[(size_t)i * CH + ch];
    } else {
        prev = prevA[(size_t)i * CH2 + t];
    }
    float t2 = 2.f * sum - prev;
    dst[(size_t)i * CH2 + t] = t2;
    size_t aidx = (size_t)(isReal ? 0 : 1) * N * CH + (size_t)i * CH + ch;
    acc[aidx] += c[k] * t2;
}

// ---------------- Complex GEMM + SiLU (in-place over acc in d_out) ----------------
// yr = accr @ Wr^T - acci @ Wi^T ; yi = accr @ Wi^T + acci @ Wr^T ; out = silu(y)
// Block handles 16 rows; reads only its own rows, writes only its own rows.
__global__ __launch_bounds__(256) void gemm_silu_k(
        const float* __restrict__ Wr, const float* __restrict__ Wi,
        float* __restrict__ out, int N) {
    __shared__ float accr[16][CH];
    __shared__ float acci[16][CH];
    int t = threadIdx.x;
    int row0 = blockIdx.x * 16;
    bool isReal = t < CH;
    int ch = t & (CH - 1);
    // load 16 rows of acc (real + imag) into LDS
    for (int r = 0; r < 16; r++) {
        int i = row0 + r;
        if (i < N) {
            float v = out[(size_t)(isReal ? 0 : 1) * N * CH + (size_t)i * CH + ch];
            if (isReal) accr[r][ch] = v; else acci[r][ch] = v;
        } else {
            if (isReal) accr[r][ch] = 0.f; else acci[r][ch] = 0.f;
        }
    }
    __syncthreads();

    const float* W1 = isReal ? Wr : Wi;   // multiplies accr
    const float* W2 = isReal ? Wi : Wr;   // multiplies acci
    float s2 = isReal ? -1.f : 1.f;

    float y[16];
    #pragma unroll
    for (int r = 0; r < 16; r++) y[r] = 0.f;

    const float* w1p = W1 + (size_t)ch * CH;
    const float* w2p = W2 + (size_t)ch * CH;
    for (int k = 0; k < CH; k += 4) {
        float4 w1 = *reinterpret_cast<const float4*>(w1p + k);
        float4 w2 = *reinterpret_cast<const float4*>(w2p + k);
        w2.x *= s2; w2.y *= s2; w2.z *= s2; w2.w *= s2;
        #pragma unroll
        for (int r = 0; r < 16; r++) {
            float4 ar = *reinterpret_cast<const float4*>(&accr[r][k]);
            float4 ai = *reinterpret_cast<const float4*>(&acci[r][k]);
            y[r] += ar.x * w1.x + ai.x * w2.x;
            y[r] += ar.y * w1.y + ai.y * w2.y;
            y[r] += ar.z * w1.z + ai.z * w2.z;
            y[r] += ar.w * w1.w + ai.w * w2.w;
        }
    }

    #pragma unroll
    for (int r = 0; r < 16; r++) {
        int i = row0 + r;
        if (i < N) {
            float v = y[r];
            float sv = v / (1.f + expf(-v));   // SiLU
            out[(size_t)(isReal ? 0 : 1) * N * CH + (size_t)i * CH + ch] = sv;
        }
    }
}

// ---------------- launch ----------------

extern "C" void kernel_launch(void* const* d_in, const int* in_sizes, int n_in,
                              void* d_out, int out_size, void* d_ws, size_t ws_size,
                              hipStream_t stream) {
    const float* xr     = (const float*)d_in[0];
    const float* xi     = (const float*)d_in[1];
    const int*   eidx   = (const int*)d_in[2];
    const float* ew     = (const float*)d_in[3];
    const float* approx = (const float*)d_in[4];
    const float* theta  = (const float*)d_in[5];
    const float* Wr     = (const float*)d_in[6];
    const float* Wi     = (const float*)d_in[7];

    const int N = in_sizes[0] / CH;
    const int E = in_sizes[3];
    const int* rowv = eidx;       // edge_index[0]
    const int* colv = eidx + E;   // edge_index[1]

    float* outp = (float*)d_out;

    // workspace carve-up (256B aligned)
    char* w8 = (char*)d_ws;
    size_t off = 0;
    auto alloc = [&](size_t bytes) -> void* {
        void* p = w8 + off;
        off += (bytes + 255) & ~(size_t)255;
        return p;
    };
    float* c_coef   = (float*)alloc(64 * 4);
    int*   row_cnt  = (int*)alloc((size_t)N * 4);
    int*   row_start= (int*)alloc((size_t)(N + 1) * 4);
    int*   edge_pos = (int*)alloc((size_t)N * 4);
    int*   partials = (int*)alloc(256 * 4);
    int*   poff     = (int*)alloc(256 * 4);
    int*   csr_col  = (int*)alloc((size_t)E * 4);
    float* csr_w    = (float*)alloc((size_t)E * 4);
    float* bufA     = (float*)alloc((size_t)N * CH2 * 4);
    float* bufB     = (float*)alloc((size_t)N * CH2 * 4);
    (void)ws_size;

    const int NB = (N + 1023) / 1024;

    coef_k<<<1, 64, 0, stream>>>(approx, theta, c_coef);
    zero_counts_k<<<(N + 255) / 256, 256, 0, stream>>>(row_cnt, N);
    hist_k<<<(E + 255) / 256, 256, 0, stream>>>(rowv, row_cnt, E);
    scan_partial_k<<<NB, 256, 0, stream>>>(row_cnt, partials, N);
    scan_toplevel_k<<<1, 64, 0, stream>>>(partials, poff, NB);
    scan_write_k<<<NB, 256, 0, stream>>>(row_cnt, poff, row_start, edge_pos, N, E);
    scatter_k<<<(E + 255) / 256, 256, 0, stream>>>(rowv, colv, ew, edge_pos, csr_col, csr_w, E);

    // Chebyshev recurrence with B = -A. acc lives in d_out as [2][N][CH].
    // step1: T1 = B x       -> bufB
    spmm_first_k<<<N, 256, 0, stream>>>(xr, xi, row_start, csr_col, csr_w, c_coef, bufB, outp, N);
    // step2 (k=2): T2 = 2B*bufB - x    -> bufA
    spmm_step_k<<<N, 256, 0, stream>>>(bufB, xr, xi, row_start, csr_col, csr_w, c_coef, 2, bufA, outp, N);
    // step3 (k=3): T2 = 2B*bufA - bufB -> bufB (own-row overwrite, safe)
    spmm_step_k<<<N, 256, 0, stream>>>(bufA, bufB, nullptr, row_start, csr_col, csr_w, c_coef, 3, bufB, outp, N);
    // step4 (k=4): T2 = 2B*bufB - bufA -> bufA
    spmm_step_k<<<N, 256, 0, stream>>>(bufB, bufA, nullptr, row_start, csr_col, csr_w, c_coef, 4, bufA, outp, N);
    // step5 (k=5): T2 = 2B*bufA - bufB -> bufB
    spmm_step_k<<<N, 256, 0, stream>>>(bufA, bufB, nullptr, row_start, csr_col, csr_w, c_coef, 5, bufB, outp, N);

    // complex linear + SiLU, in-place over acc in d_out
    gemm_silu_k<<<(N + 15) / 16, 256, 0, stream>>>(Wr, Wi, outp, N);
}

// Round 2
// 1074.368 us; speedup vs baseline: 1.8579x; 1.8579x over previous
//
#include <hip/hip_runtime.h>
#include <hip/hip_fp16.h>
#include <math.h>

// FrameletLayer: Chebyshev framelet graph conv + complex linear + CSiLU.
// C=128 channels, K=6, F=4, S=1.0. Real+imag fused as [N][256] (=128 half2) rows.
// Scaled recurrence: That_k = T_k / 32^k  =>  That_k = (B/16)*That_{k-1} - That_{k-2}/1024
// with csr_w storing B/16 entries (= -w/16). Stored iterates are O(1) -> fp16-safe.

#define CH   128
#define CH2  256
#define NP   128   // half2 lanes per row (256 half = 128 half2)

// ---------------- CSR build ----------------

__global__ void zero_counts_k(int* cnt, int n) {
    int i = blockIdx.x * blockDim.x + threadIdx.x;
    if (i < n) cnt[i] = 0;
}

__global__ void hist_k(const int* __restrict__ row, int* cnt, int E) {
    int e = blockIdx.x * blockDim.x + threadIdx.x;
    if (e < E) atomicAdd(&cnt[row[e]], 1);
}

__global__ void scan_partial_k(const int* __restrict__ cnt, int* partials, int N) {
    __shared__ int sd[256];
    int t = threadIdx.x;
    int base = blockIdx.x * 1024;
    int s = 0;
    #pragma unroll
    for (int j = 0; j < 4; j++) {
        int i = base + t * 4 + j;
        if (i < N) s += cnt[i];
    }
    sd[t] = s;
    __syncthreads();
    for (int off = 128; off > 0; off >>= 1) {
        if (t < off) sd[t] += sd[t + off];
        __syncthreads();
    }
    if (t == 0) partials[blockIdx.x] = sd[0];
}

__global__ void scan_toplevel_k(const int* __restrict__ partials, int* poff, int nb) {
    if (threadIdx.x == 0 && blockIdx.x == 0) {
        int run = 0;
        for (int b = 0; b < nb; b++) { poff[b] = run; run += partials[b]; }
    }
}

__global__ void scan_write_k(const int* __restrict__ cnt, const int* __restrict__ poff,
                             int* row_start, int* edge_pos, int N, int E) {
    __shared__ int sd[256];
    int t = threadIdx.x;
    int base = blockIdx.x * 1024;
    int v[4];
    int s = 0;
    #pragma unroll
    for (int j = 0; j < 4; j++) {
        int i = base + t * 4 + j;
        v[j] = (i < N) ? cnt[i] : 0;
        s += v[j];
    }
    sd[t] = s;
    __syncthreads();
    for (int off = 1; off < 256; off <<= 1) {
        int y = (t >= off) ? sd[t - off] : 0;
        __syncthreads();
        sd[t] += y;
        __syncthreads();
    }
    int run = poff[blockIdx.x] + ((t == 0) ? 0 : sd[t - 1]);
    #pragma unroll
    for (int j = 0; j < 4; j++) {
        int i = base + t * 4 + j;
        if (i < N) { row_start[i] = run; edge_pos[i] = run; run += v[j]; }
    }
    if (blockIdx.x == 0 && t == 0) row_start[N] = E;
}

__global__ void scatter_k(const int* __restrict__ row, const int* __restrict__ col,
                          const float* __restrict__ w, int* edge_pos,
                          int* csr_col, float* csr_w, int E) {
    int e = blockIdx.x * blockDim.x + threadIdx.x;
    if (e < E) {
        int r = row[e];
        int p = atomicAdd(&edge_pos[r], 1);
        csr_col[p] = col[e];
        csr_w[p]   = -w[e] * (1.0f / 16.0f);   // B/16 entries
    }
}

// cp[k] = (sum_f theta[f]*approx[f][k]) * 32^k
__global__ void coef_k(const float* __restrict__ approx, const float* __restrict__ theta,
                       float* cp) {
    int k = threadIdx.x;
    if (k < 6 && blockIdx.x == 0) {
        float s = 0.f;
        for (int f = 0; f < 4; f++) s += theta[f] * approx[f * 6 + k];
        float sc = 1.f;
        for (int j = 0; j < k; j++) sc *= 32.f;
        cp[k] = s * sc;
    }
}

// x (fp32 xr,xi) -> fused fp16 [N][128 half2]: p<64 real pair, p>=64 imag pair
__global__ void convert_x_k(const float2* __restrict__ xr2, const float2* __restrict__ xi2,
                            __half2* __restrict__ xbuf, int total) {
    int idx = blockIdx.x * blockDim.x + threadIdx.x;
    if (idx >= total) return;
    int i = idx >> 7;
    int p = idx & 127;
    float2 v = (p < 64) ? xr2[(size_t)i * 64 + p] : xi2[(size_t)i * 64 + (p - 64)];
    xbuf[idx] = __floats2half2_rn(v.x, v.y);
}

// ---------------- SpMM steps (half2 gather, 2 rows per block) ----------------

// That1 = (B/32) x = 0.5*sum ; acc = cp0*x + cp1*That1
__global__ __launch_bounds__(256) void spmm_first2_k(
        const __half2* __restrict__ xbuf,
        const int* __restrict__ row_start, const int* __restrict__ csr_col,
        const float* __restrict__ csr_w, const float* __restrict__ cp,
        __half2* __restrict__ t1, float2* __restrict__ acc2, int N) {
    int t = threadIdx.x;
    int rl = t >> 7;
    int p  = t & 127;
    int i = blockIdx.x * 2 + rl;
    if (i >= N) return;
    int beg = row_start[i], end = row_start[i + 1];
    float s0 = 0.f, s1 = 0.f;
    int e = beg;
    for (; e + 4 <= end; e += 4) {
        int ca = csr_col[e], cb = csr_col[e+1], cc = csr_col[e+2], cd = csr_col[e+3];
        float wa = csr_w[e], wb = csr_w[e+1], wc = csr_w[e+2], wd = csr_w[e+3];
        float2 fa = __half22float2(xbuf[(size_t)ca * NP + p]);
        float2 fb = __half22float2(xbuf[(size_t)cb * NP + p]);
        float2 fc = __half22float2(xbuf[(size_t)cc * NP + p]);
        float2 fd = __half22float2(xbuf[(size_t)cd * NP + p]);
        s0 += wa * fa.x + wb * fb.x + wc * fc.x + wd * fd.x;
        s1 += wa * fa.y + wb * fb.y + wc * fc.y + wd * fd.y;
    }
    for (; e < end; e++) {
        int ca = csr_col[e];
        float wa = csr_w[e];
        float2 fa = __half22float2(xbuf[(size_t)ca * NP + p]);
        s0 += wa * fa.x;
        s1 += wa * fa.y;
    }
    s0 *= 0.5f; s1 *= 0.5f;                    // B/16 -> B/32
    t1[(size_t)i * NP + p] = __floats2half2_rn(s0, s1);
    float2 fo = __half22float2(xbuf[(size_t)i * NP + p]);
    int half = p >> 6, q = p & 63;
    float cp0 = cp[0], cp1 = cp[1];
    float2 a;
    a.x = cp0 * fo.x + cp1 * s0;
    a.y = cp0 * fo.y + cp1 * s1;
    acc2[(size_t)half * N * 64 + (size_t)i * 64 + q] = a;
}

// That_k = (B/16)*cur - prev/1024 ; acc += cp[k]*That_k ; optional dst write
__global__ __launch_bounds__(256) void spmm_step2_k(
        const __half2* __restrict__ cur, const __half2* __restrict__ prev,
        const int* __restrict__ row_start, const int* __restrict__ csr_col,
        const float* __restrict__ csr_w, const float* __restrict__ cp, int k,
        __half2* __restrict__ dst, float2* __restrict__ acc2, int N, int writeDst) {
    int t = threadIdx.x;
    int rl = t >> 7;
    int p  = t & 127;
    int i = blockIdx.x * 2 + rl;
    if (i >= N) return;
    int beg = row_start[i], end = row_start[i + 1];
    float s0 = 0.f, s1 = 0.f;
    int e = beg;
    for (; e + 4 <= end; e += 4) {
        int ca = csr_col[e], cb = csr_col[e+1], cc = csr_col[e+2], cd = csr_col[e+3];
        float wa = csr_w[e], wb = csr_w[e+1], wc = csr_w[e+2], wd = csr_w[e+3];
        float2 fa = __half22float2(cur[(size_t)ca * NP + p]);
        float2 fb = __half22float2(cur[(size_t)cb * NP + p]);
        float2 fc = __half22float2(cur[(size_t)cc * NP + p]);
        float2 fd = __half22float2(cur[(size_t)cd * NP + p]);
        s0 += wa * fa.x + wb * fb.x + wc * fc.x + wd * fd.x;
        s1 += wa * fa.y + wb * fb.y + wc * fc.y + wd * fd.y;
    }
    for (; e < end; e++) {
        int ca = csr_col[e];
        float wa = csr_w[e];
        float2 fa = __half22float2(cur[(size_t)ca * NP + p]);
        s0 += wa * fa.x;
        s1 += wa * fa.y;
    }
    float2 fp2 = __half22float2(prev[(size_t)i * NP + p]);
    const float inv = 1.0f / 1024.0f;
    float t2x = s0 - inv * fp2.x;
    float t2y = s1 - inv * fp2.y;
    if (writeDst) dst[(size_t)i * NP + p] = __floats2half2_rn(t2x, t2y);
    float ck = cp[k];
    int half = p >> 6, q = p & 63;
    size_t aidx = (size_t)half * N * 64 + (size_t)i * 64 + q;
    float2 a = acc2[aidx];
    a.x += ck * t2x;
    a.y += ck * t2y;
    acc2[aidx] = a;
}

// ---------------- Complex GEMM + SiLU (in-place over acc in d_out) ----------------
__global__ __launch_bounds__(256) void gemm_silu_k(
        const float* __restrict__ Wr, const float* __restrict__ Wi,
        float* __restrict__ out, int N) {
    __shared__ float accr[16][CH];
    __shared__ float acci[16][CH];
    int t = threadIdx.x;
    int row0 = blockIdx.x * 16;
    bool isReal = t < CH;
    int ch = t & (CH - 1);
    for (int r = 0; r < 16; r++) {
        int i = row0 + r;
        float v = 0.f;
        if (i < N) v = out[(size_t)(isReal ? 0 : 1) * N * CH + (size_t)i * CH + ch];
        if (isReal) accr[r][ch] = v; else acci[r][ch] = v;
    }
    __syncthreads();

    const float* W1 = isReal ? Wr : Wi;
    const float* W2 = isReal ? Wi : Wr;
    float s2 = isReal ? -1.f : 1.f;

    float y[16];
    #pragma unroll
    for (int r = 0; r < 16; r++) y[r] = 0.f;

    const float* w1p = W1 + (size_t)ch * CH;
    const float* w2p = W2 + (size_t)ch * CH;
    for (int k = 0; k < CH; k += 4) {
        float4 w1 = *reinterpret_cast<const float4*>(w1p + k);
        float4 w2 = *reinterpret_cast<const float4*>(w2p + k);
        w2.x *= s2; w2.y *= s2; w2.z *= s2; w2.w *= s2;
        #pragma unroll
        for (int r = 0; r < 16; r++) {
            float4 ar = *reinterpret_cast<const float4*>(&accr[r][k]);
            float4 ai = *reinterpret_cast<const float4*>(&acci[r][k]);
            y[r] += ar.x * w1.x + ai.x * w2.x;
            y[r] += ar.y * w1.y + ai.y * w2.y;
            y[r] += ar.z * w1.z + ai.z * w2.z;
            y[r] += ar.w * w1.w + ai.w * w2.w;
        }
    }

    #pragma unroll
    for (int r = 0; r < 16; r++) {
        int i = row0 + r;
        if (i < N) {
            float v = y[r];
            float sv = v / (1.f + expf(-v));
            out[(size_t)(isReal ? 0 : 1) * N * CH + (size_t)i * CH + ch] = sv;
        }
    }
}

// ---------------- launch ----------------

extern "C" void kernel_launch(void* const* d_in, const int* in_sizes, int n_in,
                              void* d_out, int out_size, void* d_ws, size_t ws_size,
                              hipStream_t stream) {
    const float* xr     = (const float*)d_in[0];
    const float* xi     = (const float*)d_in[1];
    const int*   eidx   = (const int*)d_in[2];
    const float* ew     = (const float*)d_in[3];
    const float* approx = (const float*)d_in[4];
    const float* theta  = (const float*)d_in[5];
    const float* Wr     = (const float*)d_in[6];
    const float* Wi     = (const float*)d_in[7];

    const int N = in_sizes[0] / CH;
    const int E = in_sizes[3];
    const int* rowv = eidx;
    const int* colv = eidx + E;

    float*  outp = (float*)d_out;
    float2* acc2 = (float2*)d_out;

    char* w8 = (char*)d_ws;
    size_t off = 0;
    auto alloc = [&](size_t bytes) -> void* {
        void* ptr = w8 + off;
        off += (bytes + 255) & ~(size_t)255;
        return ptr;
    };
    float*   cp       = (float*)alloc(64 * 4);
    int*     row_cnt  = (int*)alloc((size_t)N * 4);
    int*     row_start= (int*)alloc((size_t)(N + 1) * 4);
    int*     edge_pos = (int*)alloc((size_t)N * 4);
    int*     partials = (int*)alloc(256 * 4);
    int*     poff     = (int*)alloc(256 * 4);
    int*     csr_col  = (int*)alloc((size_t)E * 4);
    float*   csr_w    = (float*)alloc((size_t)E * 4);
    __half2* xbuf     = (__half2*)alloc((size_t)N * NP * 4);
    __half2* bufA     = (__half2*)alloc((size_t)N * NP * 4);
    __half2* bufB     = (__half2*)alloc((size_t)N * NP * 4);
    (void)ws_size;

    const int NB = (N + 1023) / 1024;
    const int NH = N * NP;      // total half2 elements

    coef_k<<<1, 64, 0, stream>>>(approx, theta, cp);
    zero_counts_k<<<(N + 255) / 256, 256, 0, stream>>>(row_cnt, N);
    hist_k<<<(E + 255) / 256, 256, 0, stream>>>(rowv, row_cnt, E);
    scan_partial_k<<<NB, 256, 0, stream>>>(row_cnt, partials, N);
    scan_toplevel_k<<<1, 64, 0, stream>>>(partials, poff, NB);
    scan_write_k<<<NB, 256, 0, stream>>>(row_cnt, poff, row_start, edge_pos, N, E);
    scatter_k<<<(E + 255) / 256, 256, 0, stream>>>(rowv, colv, ew, edge_pos, csr_col, csr_w, E);
    convert_x_k<<<(NH + 255) / 256, 256, 0, stream>>>((const float2*)xr, (const float2*)xi, xbuf, NH);

    const int NG = (N + 1) / 2;   // 2 rows per block

    // step1: That1 -> bufB
    spmm_first2_k<<<NG, 256, 0, stream>>>(xbuf, row_start, csr_col, csr_w, cp, bufB, acc2, N);
    // step2 (k=2): That2 = (B/16)That1 - x/1024 -> bufA
    spmm_step2_k<<<NG, 256, 0, stream>>>(bufB, xbuf, row_start, csr_col, csr_w, cp, 2, bufA, acc2, N, 1);
    // step3 (k=3): -> bufB (own-row overwrite safe)
    spmm_step2_k<<<NG, 256, 0, stream>>>(bufA, bufB, row_start, csr_col, csr_w, cp, 3, bufB, acc2, N, 1);
    // step4 (k=4): -> bufA
    spmm_step2_k<<<NG, 256, 0, stream>>>(bufB, bufA, row_start, csr_col, csr_w, cp, 4, bufA, acc2, N, 1);
    // step5 (k=5): dst not needed
    spmm_step2_k<<<NG, 256, 0, stream>>>(bufA, bufB, row_start, csr_col, csr_w, cp, 5, bufB, acc2, N, 0);

    gemm_silu_k<<<(N + 15) / 16, 256, 0, stream>>>(Wr, Wi, outp, N);
}

// Round 3
// 854.754 us; speedup vs baseline: 2.3352x; 1.2569x over previous
//
#include <hip/hip_runtime.h>
#include <hip/hip_fp16.h>
#include <math.h>

// FrameletLayer: Chebyshev framelet graph conv + complex linear + CSiLU.
// Scaled recurrence That_k = T_k/32^k (fp16-safe); MFMA f16 for the complex GEMM.

#define CH   128
#define NP   128   // half2 lanes per row (256 half)
#define NP4  64    // half4 lanes per row

typedef _Float16 half8 __attribute__((ext_vector_type(8)));
typedef float f32x4 __attribute__((ext_vector_type(4)));

// ---------------- CSR build ----------------

__global__ void zero_counts_k(int* cnt, int n) {
    int i = blockIdx.x * blockDim.x + threadIdx.x;
    if (i < n) cnt[i] = 0;
}

__global__ void hist_k(const int* __restrict__ row, int* cnt, int E) {
    int e = blockIdx.x * blockDim.x + threadIdx.x;
    if (e < E) atomicAdd(&cnt[row[e]], 1);
}

__global__ void scan_partial_k(const int* __restrict__ cnt, int* partials, int N) {
    __shared__ int sd[256];
    int t = threadIdx.x;
    int base = blockIdx.x * 1024;
    int s = 0;
    #pragma unroll
    for (int j = 0; j < 4; j++) {
        int i = base + t * 4 + j;
        if (i < N) s += cnt[i];
    }
    sd[t] = s;
    __syncthreads();
    for (int off = 128; off > 0; off >>= 1) {
        if (t < off) sd[t] += sd[t + off];
        __syncthreads();
    }
    if (t == 0) partials[blockIdx.x] = sd[0];
}

__global__ void scan_toplevel_k(const int* __restrict__ partials, int* poff, int nb) {
    if (threadIdx.x == 0 && blockIdx.x == 0) {
        int run = 0;
        for (int b = 0; b < nb; b++) { poff[b] = run; run += partials[b]; }
    }
}

__global__ void scan_write_k(const int* __restrict__ cnt, const int* __restrict__ poff,
                             int* row_start, int* edge_pos, int N, int E) {
    __shared__ int sd[256];
    int t = threadIdx.x;
    int base = blockIdx.x * 1024;
    int v[4];
    int s = 0;
    #pragma unroll
    for (int j = 0; j < 4; j++) {
        int i = base + t * 4 + j;
        v[j] = (i < N) ? cnt[i] : 0;
        s += v[j];
    }
    sd[t] = s;
    __syncthreads();
    for (int off = 1; off < 256; off <<= 1) {
        int y = (t >= off) ? sd[t - off] : 0;
        __syncthreads();
        sd[t] += y;
        __syncthreads();
    }
    int run = poff[blockIdx.x] + ((t == 0) ? 0 : sd[t - 1]);
    #pragma unroll
    for (int j = 0; j < 4; j++) {
        int i = base + t * 4 + j;
        if (i < N) { row_start[i] = run; edge_pos[i] = run; run += v[j]; }
    }
    if (blockIdx.x == 0 && t == 0) row_start[N] = E;
}

__global__ void scatter_k(const int* __restrict__ row, const int* __restrict__ col,
                          const float* __restrict__ w, int* edge_pos,
                          int* csr_col, float* csr_w, int E) {
    int e = blockIdx.x * blockDim.x + threadIdx.x;
    if (e < E) {
        int r = row[e];
        int p = atomicAdd(&edge_pos[r], 1);
        csr_col[p] = col[e];
        csr_w[p]   = -w[e] * (1.0f / 16.0f);   // B/16 entries
    }
}

// cp[k] = (sum_f theta[f]*approx[f][k]) * 32^k
__global__ void coef_k(const float* __restrict__ approx, const float* __restrict__ theta,
                       float* cp) {
    int k = threadIdx.x;
    if (k < 6 && blockIdx.x == 0) {
        float s = 0.f;
        for (int f = 0; f < 4; f++) s += theta[f] * approx[f * 6 + k];
        float sc = 1.f;
        for (int j = 0; j < k; j++) sc *= 32.f;
        cp[k] = s * sc;
    }
}

// x (fp32 xr,xi) -> fused fp16 [N][128 half2]: p<64 real pair, p>=64 imag pair
__global__ void convert_x_k(const float2* __restrict__ xr2, const float2* __restrict__ xi2,
                            __half2* __restrict__ xbuf, int total) {
    int idx = blockIdx.x * blockDim.x + threadIdx.x;
    if (idx >= total) return;
    int i = idx >> 7;
    int p = idx & 127;
    float2 v = (p < 64) ? xr2[(size_t)i * 64 + p] : xi2[(size_t)i * 64 + (p - 64)];
    xbuf[idx] = __floats2half2_rn(v.x, v.y);
}

// WhT[j*256+k] = Wbig[k][j]; Wbig = [[Wr^T, Wi^T],[-Wi^T, Wr^T]] (k = input dim)
__global__ void build_whT_k(const float* __restrict__ Wr, const float* __restrict__ Wi,
                            _Float16* __restrict__ WhT) {
    int idx = blockIdx.x * 256 + threadIdx.x;   // 256 blocks x 256
    int j = idx >> 8, k = idx & 255;
    float v;
    if (j < 128) {
        v = (k < 128) ? Wr[j * 128 + k] : -Wi[j * 128 + (k - 128)];
    } else {
        v = (k < 128) ? Wi[(j - 128) * 128 + k] : Wr[(j - 128) * 128 + (k - 128)];
    }
    WhT[idx] = (_Float16)v;
}

// ---------------- SpMM steps (half4 gather, 4 rows/block, 64 lanes/row) ----------------

__device__ __forceinline__ void unpack4(uint2 v, float& a, float& b, float& c, float& d) {
    __half2 lo = *reinterpret_cast<__half2*>(&v.x);
    __half2 hi = *reinterpret_cast<__half2*>(&v.y);
    float2 f0 = __half22float2(lo);
    float2 f1 = __half22float2(hi);
    a = f0.x; b = f0.y; c = f1.x; d = f1.y;
}

// That1 = (B/32) x ; acc = cp0*x + cp1*That1
__global__ __launch_bounds__(256) void spmm_first4_k(
        const uint2* __restrict__ xb4,
        const int* __restrict__ row_start, const int* __restrict__ csr_col,
        const float* __restrict__ csr_w, const float* __restrict__ cp,
        uint2* __restrict__ t1, float4* __restrict__ acc4, int N) {
    int t = threadIdx.x;
    int rl = t >> 6;
    int p4 = t & 63;
    int i = blockIdx.x * 4 + rl;
    if (i >= N) return;
    int beg = row_start[i], end = row_start[i + 1];
    float s0 = 0.f, s1 = 0.f, s2 = 0.f, s3 = 0.f;
    int e = beg;
    for (; e + 4 <= end; e += 4) {
        int ca = csr_col[e], cb = csr_col[e+1], cc = csr_col[e+2], cd = csr_col[e+3];
        float wa = csr_w[e], wb = csr_w[e+1], wc = csr_w[e+2], wd = csr_w[e+3];
        float a0,a1,a2,a3, b0,b1,b2,b3, c0,c1,c2,c3, d0,d1,d2,d3;
        unpack4(xb4[(size_t)ca * NP4 + p4], a0,a1,a2,a3);
        unpack4(xb4[(size_t)cb * NP4 + p4], b0,b1,b2,b3);
        unpack4(xb4[(size_t)cc * NP4 + p4], c0,c1,c2,c3);
        unpack4(xb4[(size_t)cd * NP4 + p4], d0,d1,d2,d3);
        s0 += wa*a0 + wb*b0 + wc*c0 + wd*d0;
        s1 += wa*a1 + wb*b1 + wc*c1 + wd*d1;
        s2 += wa*a2 + wb*b2 + wc*c2 + wd*d2;
        s3 += wa*a3 + wb*b3 + wc*c3 + wd*d3;
    }
    for (; e < end; e++) {
        int ca = csr_col[e];
        float wa = csr_w[e];
        float a0,a1,a2,a3;
        unpack4(xb4[(size_t)ca * NP4 + p4], a0,a1,a2,a3);
        s0 += wa*a0; s1 += wa*a1; s2 += wa*a2; s3 += wa*a3;
    }
    s0 *= 0.5f; s1 *= 0.5f; s2 *= 0.5f; s3 *= 0.5f;   // B/16 -> B/32
    uint2 pk;
    __half2 h0 = __floats2half2_rn(s0, s1);
    __half2 h1 = __floats2half2_rn(s2, s3);
    pk.x = *reinterpret_cast<unsigned*>(&h0);
    pk.y = *reinterpret_cast<unsigned*>(&h1);
    t1[(size_t)i * NP4 + p4] = pk;
    float o0,o1,o2,o3;
    unpack4(xb4[(size_t)i * NP4 + p4], o0,o1,o2,o3);
    float cp0 = cp[0], cp1 = cp[1];
    int half = p4 >> 5, q = p4 & 31;
    float4 a;
    a.x = cp0 * o0 + cp1 * s0;
    a.y = cp0 * o1 + cp1 * s1;
    a.z = cp0 * o2 + cp1 * s2;
    a.w = cp0 * o3 + cp1 * s3;
    acc4[(size_t)half * N * 32 + (size_t)i * 32 + q] = a;
}

// That_k = (B/16)*cur - prev/1024 ; acc += cp[k]*That_k ; optional dst write
__global__ __launch_bounds__(256) void spmm_step4_k(
        const uint2* __restrict__ cur, const uint2* __restrict__ prev,
        const int* __restrict__ row_start, const int* __restrict__ csr_col,
        const float* __restrict__ csr_w, const float* __restrict__ cp, int k,
        uint2* __restrict__ dst, float4* __restrict__ acc4, int N, int writeDst) {
    int t = threadIdx.x;
    int rl = t >> 6;
    int p4 = t & 63;
    int i = blockIdx.x * 4 + rl;
    if (i >= N) return;
    int beg = row_start[i], end = row_start[i + 1];
    float s0 = 0.f, s1 = 0.f, s2 = 0.f, s3 = 0.f;
    int e = beg;
    for (; e + 4 <= end; e += 4) {
        int ca = csr_col[e], cb = csr_col[e+1], cc = csr_col[e+2], cd = csr_col[e+3];
        float wa = csr_w[e], wb = csr_w[e+1], wc = csr_w[e+2], wd = csr_w[e+3];
        float a0,a1,a2,a3, b0,b1,b2,b3, c0,c1,c2,c3, d0,d1,d2,d3;
        unpack4(cur[(size_t)ca * NP4 + p4], a0,a1,a2,a3);
        unpack4(cur[(size_t)cb * NP4 + p4], b0,b1,b2,b3);
        unpack4(cur[(size_t)cc * NP4 + p4], c0,c1,c2,c3);
        unpack4(cur[(size_t)cd * NP4 + p4], d0,d1,d2,d3);
        s0 += wa*a0 + wb*b0 + wc*c0 + wd*d0;
        s1 += wa*a1 + wb*b1 + wc*c1 + wd*d1;
        s2 += wa*a2 + wb*b2 + wc*c2 + wd*d2;
        s3 += wa*a3 + wb*b3 + wc*c3 + wd*d3;
    }
    for (; e < end; e++) {
        int ca = csr_col[e];
        float wa = csr_w[e];
        float a0,a1,a2,a3;
        unpack4(cur[(size_t)ca * NP4 + p4], a0,a1,a2,a3);
        s0 += wa*a0; s1 += wa*a1; s2 += wa*a2; s3 += wa*a3;
    }
    float p0,p1,p2,p3;
    unpack4(prev[(size_t)i * NP4 + p4], p0,p1,p2,p3);
    const float inv = 1.0f / 1024.0f;
    float t0 = s0 - inv * p0;
    float t1v = s1 - inv * p1;
    float t2v = s2 - inv * p2;
    float t3v = s3 - inv * p3;
    if (writeDst) {
        uint2 pk;
        __half2 h0 = __floats2half2_rn(t0, t1v);
        __half2 h1 = __floats2half2_rn(t2v, t3v);
        pk.x = *reinterpret_cast<unsigned*>(&h0);
        pk.y = *reinterpret_cast<unsigned*>(&h1);
        dst[(size_t)i * NP4 + p4] = pk;
    }
    float ck = cp[k];
    int half = p4 >> 5, q = p4 & 31;
    size_t aidx = (size_t)half * N * 32 + (size_t)i * 32 + q;
    float4 a = acc4[aidx];
    a.x += ck * t0;
    a.y += ck * t1v;
    a.z += ck * t2v;
    a.w += ck * t3v;
    acc4[aidx] = a;
}

// ---------------- MFMA complex GEMM + SiLU (in-place over acc in d_out) ----------------
// U[i][k] = acc/32 in f16 (k<128 real, else imag); Y = U @ Wbig; out = silu(32*Y).
__global__ __launch_bounds__(256) void gemm_silu_mfma_k(
        const _Float16* __restrict__ WhT,   // [j][k] = Wbig[k][j], 256x256
        float* __restrict__ out, int N) {
    __shared__ _Float16 U[32][264];         // pad 8 f16 -> 2-way-free banks
    int t = threadIdx.x;
    int row0 = blockIdx.x * 32;
    const float4* out4 = (const float4*)out;
    const float isc = 1.0f / 32.0f;
    // stage 32 rows x 256 k (f32 -> f16/32): 2048 float4, 8 per thread
    for (int q = t; q < 2048; q += 256) {
        int r = q >> 6;
        int kq = q & 63;                    // float4 index within row, k = kq*4
        int row = row0 + r;
        float4 v = make_float4(0.f, 0.f, 0.f, 0.f);
        if (row < N) {
            int half = kq >> 5;
            v = out4[(size_t)half * N * 32 + (size_t)row * 32 + (kq & 31)];
        }
        int k = kq * 4;
        U[r][k]   = (_Float16)(v.x * isc);
        U[r][k+1] = (_Float16)(v.y * isc);
        U[r][k+2] = (_Float16)(v.z * isc);
        U[r][k+3] = (_Float16)(v.w * isc);
    }
    __syncthreads();

    int wave = t >> 6;
    int lane = t & 63;
    int colbase = wave * 64;
    int lr = lane & 15;
    int lg = lane >> 4;
    f32x4 acc[2][4] = {};
    for (int kb = 0; kb < 8; kb++) {
        int k0 = kb * 32 + lg * 8;
        half8 a0 = *(const half8*)&U[lr][k0];
        half8 a1 = *(const half8*)&U[16 + lr][k0];
        #pragma unroll
        for (int nf = 0; nf < 4; nf++) {
            int col = colbase + nf * 16 + lr;
            half8 b = *(const half8*)&WhT[(size_t)col * 256 + k0];
            acc[0][nf] = __builtin_amdgcn_mfma_f32_16x16x32_f16(a0, b, acc[0][nf], 0, 0, 0);
            acc[1][nf] = __builtin_amdgcn_mfma_f32_16x16x32_f16(a1, b, acc[1][nf], 0, 0, 0);
        }
    }

    #pragma unroll
    for (int mf = 0; mf < 2; mf++) {
        #pragma unroll
        for (int nf = 0; nf < 4; nf++) {
            int col = colbase + nf * 16 + lr;
            int half = col >> 7, j = col & 127;
            #pragma unroll
            for (int r4 = 0; r4 < 4; r4++) {
                int row = row0 + mf * 16 + lg * 4 + r4;
                if (row < N) {
                    float v = acc[mf][nf][r4] * 32.f;
                    float sv = v / (1.f + expf(-v));
                    out[(size_t)half * N * CH + (size_t)row * CH + j] = sv;
                }
            }
        }
    }
}

// ---------------- launch ----------------

extern "C" void kernel_launch(void* const* d_in, const int* in_sizes, int n_in,
                              void* d_out, int out_size, void* d_ws, size_t ws_size,
                              hipStream_t stream) {
    const float* xr     = (const float*)d_in[0];
    const float* xi     = (const float*)d_in[1];
    const int*   eidx   = (const int*)d_in[2];
    const float* ew     = (const float*)d_in[3];
    const float* approx = (const float*)d_in[4];
    const float* theta  = (const float*)d_in[5];
    const float* Wr     = (const float*)d_in[6];
    const float* Wi     = (const float*)d_in[7];

    const int N = in_sizes[0] / CH;
    const int E = in_sizes[3];
    const int* rowv = eidx;
    const int* colv = eidx + E;

    float*  outp = (float*)d_out;
    float4* acc4 = (float4*)d_out;

    char* w8 = (char*)d_ws;
    size_t off = 0;
    auto alloc = [&](size_t bytes) -> void* {
        void* ptr = w8 + off;
        off += (bytes + 255) & ~(size_t)255;
        return ptr;
    };
    float*    cp       = (float*)alloc(64 * 4);
    int*      row_cnt  = (int*)alloc((size_t)N * 4);
    int*      row_start= (int*)alloc((size_t)(N + 1) * 4);
    int*      edge_pos = (int*)alloc((size_t)N * 4);
    int*      partials = (int*)alloc(256 * 4);
    int*      poff     = (int*)alloc(256 * 4);
    int*      csr_col  = (int*)alloc((size_t)E * 4);
    float*    csr_w    = (float*)alloc((size_t)E * 4);
    _Float16* WhT      = (_Float16*)alloc(256 * 256 * 2);
    __half2*  xbuf     = (__half2*)alloc((size_t)N * NP * 4);
    __half2*  bufA     = (__half2*)alloc((size_t)N * NP * 4);
    __half2*  bufB     = (__half2*)alloc((size_t)N * NP * 4);
    (void)ws_size;

    const int NB = (N + 1023) / 1024;
    const int NH = N * NP;

    coef_k<<<1, 64, 0, stream>>>(approx, theta, cp);
    build_whT_k<<<256, 256, 0, stream>>>(Wr, Wi, WhT);
    zero_counts_k<<<(N + 255) / 256, 256, 0, stream>>>(row_cnt, N);
    hist_k<<<(E + 255) / 256, 256, 0, stream>>>(rowv, row_cnt, E);
    scan_partial_k<<<NB, 256, 0, stream>>>(row_cnt, partials, N);
    scan_toplevel_k<<<1, 64, 0, stream>>>(partials, poff, NB);
    scan_write_k<<<NB, 256, 0, stream>>>(row_cnt, poff, row_start, edge_pos, N, E);
    scatter_k<<<(E + 255) / 256, 256, 0, stream>>>(rowv, colv, ew, edge_pos, csr_col, csr_w, E);
    convert_x_k<<<(NH + 255) / 256, 256, 0, stream>>>((const float2*)xr, (const float2*)xi, xbuf, NH);

    const int NG = (N + 3) / 4;   // 4 rows per block
    const uint2* xb4 = (const uint2*)xbuf;
    uint2* bA = (uint2*)bufA;
    uint2* bB = (uint2*)bufB;

    // step1: That1 -> bufB
    spmm_first4_k<<<NG, 256, 0, stream>>>(xb4, row_start, csr_col, csr_w, cp, bB, acc4, N);
    // step2 (k=2): -> bufA
    spmm_step4_k<<<NG, 256, 0, stream>>>(bB, xb4, row_start, csr_col, csr_w, cp, 2, bA, acc4, N, 1);
    // step3 (k=3): -> bufB (own-row overwrite safe)
    spmm_step4_k<<<NG, 256, 0, stream>>>(bA, bB, row_start, csr_col, csr_w, cp, 3, bB, acc4, N, 1);
    // step4 (k=4): -> bufA
    spmm_step4_k<<<NG, 256, 0, stream>>>(bB, bA, row_start, csr_col, csr_w, cp, 4, bA, acc4, N, 1);
    // step5 (k=5): dst not needed
    spmm_step4_k<<<NG, 256, 0, stream>>>(bA, bB, row_start, csr_col, csr_w, cp, 5, bB, acc4, N, 0);

    gemm_silu_mfma_k<<<(N + 31) / 32, 256, 0, stream>>>(WhT, outp, N);
}

// Round 4
// 835.938 us; speedup vs baseline: 2.3878x; 1.0225x over previous
//
#include <hip/hip_runtime.h>
#include <hip/hip_fp16.h>
#include <math.h>

// FrameletLayer: Chebyshev framelet graph conv + complex linear + CSiLU.
// Scaled recurrence That_k = T_k/32^k (fp16-safe); MFMA f16 for the complex GEMM.
// CSR stored as interleaved int2 {col, weight-bits} to halve scatter write-amp.

#define CH   128
#define NP   128   // half2 lanes per row (256 half)
#define NP4  64    // half4 lanes per row

typedef _Float16 half8 __attribute__((ext_vector_type(8)));
typedef float f32x4 __attribute__((ext_vector_type(4)));

// ---------------- CSR build ----------------

__global__ void zero_counts_k(int* cnt, int n) {
    int i = blockIdx.x * blockDim.x + threadIdx.x;
    if (i < n) cnt[i] = 0;
}

__global__ void hist_k(const int* __restrict__ row, int* cnt, int E) {
    int e = blockIdx.x * blockDim.x + threadIdx.x;
    if (e < E) atomicAdd(&cnt[row[e]], 1);
}

__global__ void scan_partial_k(const int* __restrict__ cnt, int* partials, int N) {
    __shared__ int sd[256];
    int t = threadIdx.x;
    int base = blockIdx.x * 1024;
    int s = 0;
    #pragma unroll
    for (int j = 0; j < 4; j++) {
        int i = base + t * 4 + j;
        if (i < N) s += cnt[i];
    }
    sd[t] = s;
    __syncthreads();
    for (int off = 128; off > 0; off >>= 1) {
        if (t < off) sd[t] += sd[t + off];
        __syncthreads();
    }
    if (t == 0) partials[blockIdx.x] = sd[0];
}

__global__ void scan_toplevel_k(const int* __restrict__ partials, int* poff, int nb) {
    if (threadIdx.x == 0 && blockIdx.x == 0) {
        int run = 0;
        for (int b = 0; b < nb; b++) { poff[b] = run; run += partials[b]; }
    }
}

__global__ void scan_write_k(const int* __restrict__ cnt, const int* __restrict__ poff,
                             int* row_start, int* edge_pos, int N, int E) {
    __shared__ int sd[256];
    int t = threadIdx.x;
    int base = blockIdx.x * 1024;
    int v[4];
    int s = 0;
    #pragma unroll
    for (int j = 0; j < 4; j++) {
        int i = base + t * 4 + j;
        v[j] = (i < N) ? cnt[i] : 0;
        s += v[j];
    }
    sd[t] = s;
    __syncthreads();
    for (int off = 1; off < 256; off <<= 1) {
        int y = (t >= off) ? sd[t - off] : 0;
        __syncthreads();
        sd[t] += y;
        __syncthreads();
    }
    int run = poff[blockIdx.x] + ((t == 0) ? 0 : sd[t - 1]);
    #pragma unroll
    for (int j = 0; j < 4; j++) {
        int i = base + t * 4 + j;
        if (i < N) { row_start[i] = run; edge_pos[i] = run; run += v[j]; }
    }
    if (blockIdx.x == 0 && t == 0) row_start[N] = E;
}

__global__ void scatter_k(const int* __restrict__ row, const int* __restrict__ col,
                          const float* __restrict__ w, int* edge_pos,
                          int2* __restrict__ csr, int E) {
    int e = blockIdx.x * blockDim.x + threadIdx.x;
    if (e < E) {
        int r = row[e];
        int p = atomicAdd(&edge_pos[r], 1);
        int2 v;
        v.x = col[e];
        v.y = __float_as_int(-w[e] * (1.0f / 16.0f));   // B/16 entries
        csr[p] = v;
    }
}

// cp[k] = (sum_f theta[f]*approx[f][k]) * 32^k
__global__ void coef_k(const float* __restrict__ approx, const float* __restrict__ theta,
                       float* cp) {
    int k = threadIdx.x;
    if (k < 6 && blockIdx.x == 0) {
        float s = 0.f;
        for (int f = 0; f < 4; f++) s += theta[f] * approx[f * 6 + k];
        float sc = 1.f;
        for (int j = 0; j < k; j++) sc *= 32.f;
        cp[k] = s * sc;
    }
}

// x (fp32 xr,xi) -> fused fp16 [N][128 half2]: p<64 real pair, p>=64 imag pair
__global__ void convert_x_k(const float2* __restrict__ xr2, const float2* __restrict__ xi2,
                            __half2* __restrict__ xbuf, int total) {
    int idx = blockIdx.x * blockDim.x + threadIdx.x;
    if (idx >= total) return;
    int i = idx >> 7;
    int p = idx & 127;
    float2 v = (p < 64) ? xr2[(size_t)i * 64 + p] : xi2[(size_t)i * 64 + (p - 64)];
    xbuf[idx] = __floats2half2_rn(v.x, v.y);
}

// WhT[j*256+k] = Wbig[k][j]; Wbig = [[Wr^T, Wi^T],[-Wi^T, Wr^T]] (k = input dim)
__global__ void build_whT_k(const float* __restrict__ Wr, const float* __restrict__ Wi,
                            _Float16* __restrict__ WhT) {
    int idx = blockIdx.x * 256 + threadIdx.x;
    int j = idx >> 8, k = idx & 255;
    float v;
    if (j < 128) {
        v = (k < 128) ? Wr[j * 128 + k] : -Wi[j * 128 + (k - 128)];
    } else {
        v = (k < 128) ? Wi[(j - 128) * 128 + k] : Wr[(j - 128) * 128 + (k - 128)];
    }
    WhT[idx] = (_Float16)v;
}

// ---------------- SpMM steps (half4 gather, 4 rows/block, 64 lanes/row) ----------------

__device__ __forceinline__ void unpack4(uint2 v, float& a, float& b, float& c, float& d) {
    __half2 lo = *reinterpret_cast<__half2*>(&v.x);
    __half2 hi = *reinterpret_cast<__half2*>(&v.y);
    float2 f0 = __half22float2(lo);
    float2 f1 = __half22float2(hi);
    a = f0.x; b = f0.y; c = f1.x; d = f1.y;
}

// Core gather loop: s[0..3] += sum_e w_e * cur[col_e][p4 lanes]; 4-edge groups,
// one group software-prefetched ahead so edge-pair loads overlap gathers.
__device__ __forceinline__ void gather_row(
        const uint2* __restrict__ src, const int2* __restrict__ csr,
        int beg, int end, int p4,
        float& s0, float& s1, float& s2, float& s3) {
    int e = beg;
    int2 c0, c1, c2, c3;
    if (e + 4 <= end) { c0 = csr[e]; c1 = csr[e+1]; c2 = csr[e+2]; c3 = csr[e+3]; }
    for (; e + 8 <= end; e += 4) {
        int2 n0 = csr[e+4], n1 = csr[e+5], n2 = csr[e+6], n3 = csr[e+7];
        float a0,a1,a2,a3, b0,b1,b2,b3, d0,d1,d2,d3, f0,f1,f2,f3;
        unpack4(src[(size_t)c0.x * NP4 + p4], a0,a1,a2,a3);
        unpack4(src[(size_t)c1.x * NP4 + p4], b0,b1,b2,b3);
        unpack4(src[(size_t)c2.x * NP4 + p4], d0,d1,d2,d3);
        unpack4(src[(size_t)c3.x * NP4 + p4], f0,f1,f2,f3);
        float wa = __int_as_float(c0.y), wb = __int_as_float(c1.y);
        float wc = __int_as_float(c2.y), wd = __int_as_float(c3.y);
        s0 += wa*a0 + wb*b0 + wc*d0 + wd*f0;
        s1 += wa*a1 + wb*b1 + wc*d1 + wd*f1;
        s2 += wa*a2 + wb*b2 + wc*d2 + wd*f2;
        s3 += wa*a3 + wb*b3 + wc*d3 + wd*f3;
        c0 = n0; c1 = n1; c2 = n2; c3 = n3;
    }
    if (e + 4 <= end) {
        float a0,a1,a2,a3, b0,b1,b2,b3, d0,d1,d2,d3, f0,f1,f2,f3;
        unpack4(src[(size_t)c0.x * NP4 + p4], a0,a1,a2,a3);
        unpack4(src[(size_t)c1.x * NP4 + p4], b0,b1,b2,b3);
        unpack4(src[(size_t)c2.x * NP4 + p4], d0,d1,d2,d3);
        unpack4(src[(size_t)c3.x * NP4 + p4], f0,f1,f2,f3);
        float wa = __int_as_float(c0.y), wb = __int_as_float(c1.y);
        float wc = __int_as_float(c2.y), wd = __int_as_float(c3.y);
        s0 += wa*a0 + wb*b0 + wc*d0 + wd*f0;
        s1 += wa*a1 + wb*b1 + wc*d1 + wd*f1;
        s2 += wa*a2 + wb*b2 + wc*d2 + wd*f2;
        s3 += wa*a3 + wb*b3 + wc*d3 + wd*f3;
        e += 4;
    }
    for (; e < end; e++) {
        int2 c = csr[e];
        float a0,a1,a2,a3;
        unpack4(src[(size_t)c.x * NP4 + p4], a0,a1,a2,a3);
        float wa = __int_as_float(c.y);
        s0 += wa*a0; s1 += wa*a1; s2 += wa*a2; s3 += wa*a3;
    }
}

// That1 = (B/32) x ; acc = cp0*x + cp1*That1
__global__ __launch_bounds__(256) void spmm_first4_k(
        const uint2* __restrict__ xb4,
        const int* __restrict__ row_start, const int2* __restrict__ csr,
        const float* __restrict__ cp,
        uint2* __restrict__ t1, float4* __restrict__ acc4, int N) {
    int t = threadIdx.x;
    int rl = t >> 6;
    int p4 = t & 63;
    int i = blockIdx.x * 4 + rl;
    if (i >= N) return;
    int beg = row_start[i], end = row_start[i + 1];
    float s0 = 0.f, s1 = 0.f, s2 = 0.f, s3 = 0.f;
    gather_row(xb4, csr, beg, end, p4, s0, s1, s2, s3);
    s0 *= 0.5f; s1 *= 0.5f; s2 *= 0.5f; s3 *= 0.5f;   // B/16 -> B/32
    uint2 pk;
    __half2 h0 = __floats2half2_rn(s0, s1);
    __half2 h1 = __floats2half2_rn(s2, s3);
    pk.x = *reinterpret_cast<unsigned*>(&h0);
    pk.y = *reinterpret_cast<unsigned*>(&h1);
    t1[(size_t)i * NP4 + p4] = pk;
    float o0,o1,o2,o3;
    unpack4(xb4[(size_t)i * NP4 + p4], o0,o1,o2,o3);
    float cp0 = cp[0], cp1 = cp[1];
    int half = p4 >> 5, q = p4 & 31;
    float4 a;
    a.x = cp0 * o0 + cp1 * s0;
    a.y = cp0 * o1 + cp1 * s1;
    a.z = cp0 * o2 + cp1 * s2;
    a.w = cp0 * o3 + cp1 * s3;
    acc4[(size_t)half * N * 32 + (size_t)i * 32 + q] = a;
}

// That_k = (B/16)*cur - prev/1024 ; acc += cp[k]*That_k ; optional dst write
__global__ __launch_bounds__(256) void spmm_step4_k(
        const uint2* __restrict__ cur, const uint2* __restrict__ prev,
        const int* __restrict__ row_start, const int2* __restrict__ csr,
        const float* __restrict__ cp, int k,
        uint2* __restrict__ dst, float4* __restrict__ acc4, int N, int writeDst) {
    int t = threadIdx.x;
    int rl = t >> 6;
    int p4 = t & 63;
    int i = blockIdx.x * 4 + rl;
    if (i >= N) return;
    int beg = row_start[i], end = row_start[i + 1];
    float s0 = 0.f, s1 = 0.f, s2 = 0.f, s3 = 0.f;
    gather_row(cur, csr, beg, end, p4, s0, s1, s2, s3);
    float p0,p1,p2,p3;
    unpack4(prev[(size_t)i * NP4 + p4], p0,p1,p2,p3);
    const float inv = 1.0f / 1024.0f;
    float t0 = s0 - inv * p0;
    float t1v = s1 - inv * p1;
    float t2v = s2 - inv * p2;
    float t3v = s3 - inv * p3;
    if (writeDst) {
        uint2 pk;
        __half2 h0 = __floats2half2_rn(t0, t1v);
        __half2 h1 = __floats2half2_rn(t2v, t3v);
        pk.x = *reinterpret_cast<unsigned*>(&h0);
        pk.y = *reinterpret_cast<unsigned*>(&h1);
        dst[(size_t)i * NP4 + p4] = pk;
    }
    float ck = cp[k];
    int half = p4 >> 5, q = p4 & 31;
    size_t aidx = (size_t)half * N * 32 + (size_t)i * 32 + q;
    float4 a = acc4[aidx];
    a.x += ck * t0;
    a.y += ck * t1v;
    a.z += ck * t2v;
    a.w += ck * t3v;
    acc4[aidx] = a;
}

// ---------------- MFMA complex GEMM + SiLU (in-place over acc in d_out) ----------------
__global__ __launch_bounds__(256) void gemm_silu_mfma_k(
        const _Float16* __restrict__ WhT,   // [j][k] = Wbig[k][j], 256x256
        float* __restrict__ out, int N) {
    __shared__ _Float16 U[32][264];
    int t = threadIdx.x;
    int row0 = blockIdx.x * 32;
    const float4* out4 = (const float4*)out;
    const float isc = 1.0f / 32.0f;
    for (int q = t; q < 2048; q += 256) {
        int r = q >> 6;
        int kq = q & 63;
        int row = row0 + r;
        float4 v = make_float4(0.f, 0.f, 0.f, 0.f);
        if (row < N) {
            int half = kq >> 5;
            v = out4[(size_t)half * N * 32 + (size_t)row * 32 + (kq & 31)];
        }
        int k = kq * 4;
        U[r][k]   = (_Float16)(v.x * isc);
        U[r][k+1] = (_Float16)(v.y * isc);
        U[r][k+2] = (_Float16)(v.z * isc);
        U[r][k+3] = (_Float16)(v.w * isc);
    }
    __syncthreads();

    int wave = t >> 6;
    int lane = t & 63;
    int colbase = wave * 64;
    int lr = lane & 15;
    int lg = lane >> 4;
    f32x4 acc[2][4] = {};
    for (int kb = 0; kb < 8; kb++) {
        int k0 = kb * 32 + lg * 8;
        half8 a0 = *(const half8*)&U[lr][k0];
        half8 a1 = *(const half8*)&U[16 + lr][k0];
        #pragma unroll
        for (int nf = 0; nf < 4; nf++) {
            int col = colbase + nf * 16 + lr;
            half8 b = *(const half8*)&WhT[(size_t)col * 256 + k0];
            acc[0][nf] = __builtin_amdgcn_mfma_f32_16x16x32_f16(a0, b, acc[0][nf], 0, 0, 0);
            acc[1][nf] = __builtin_amdgcn_mfma_f32_16x16x32_f16(a1, b, acc[1][nf], 0, 0, 0);
        }
    }

    #pragma unroll
    for (int mf = 0; mf < 2; mf++) {
        #pragma unroll
        for (int nf = 0; nf < 4; nf++) {
            int col = colbase + nf * 16 + lr;
            int half = col >> 7, j = col & 127;
            #pragma unroll
            for (int r4 = 0; r4 < 4; r4++) {
                int row = row0 + mf * 16 + lg * 4 + r4;
                if (row < N) {
                    float v = acc[mf][nf][r4] * 32.f;
                    float sv = v / (1.f + expf(-v));
                    out[(size_t)half * N * CH + (size_t)row * CH + j] = sv;
                }
            }
        }
    }
}

// ---------------- launch ----------------

extern "C" void kernel_launch(void* const* d_in, const int* in_sizes, int n_in,
                              void* d_out, int out_size, void* d_ws, size_t ws_size,
                              hipStream_t stream) {
    const float* xr     = (const float*)d_in[0];
    const float* xi     = (const float*)d_in[1];
    const int*   eidx   = (const int*)d_in[2];
    const float* ew     = (const float*)d_in[3];
    const float* approx = (const float*)d_in[4];
    const float* theta  = (const float*)d_in[5];
    const float* Wr     = (const float*)d_in[6];
    const float* Wi     = (const float*)d_in[7];

    const int N = in_sizes[0] / CH;
    const int E = in_sizes[3];
    const int* rowv = eidx;
    const int* colv = eidx + E;

    float*  outp = (float*)d_out;
    float4* acc4 = (float4*)d_out;

    char* w8 = (char*)d_ws;
    size_t off = 0;
    auto alloc = [&](size_t bytes) -> void* {
        void* ptr = w8 + off;
        off += (bytes + 255) & ~(size_t)255;
        return ptr;
    };
    float*    cp       = (float*)alloc(64 * 4);
    int*      row_cnt  = (int*)alloc((size_t)N * 4);
    int*      row_start= (int*)alloc((size_t)(N + 1) * 4);
    int*      edge_pos = (int*)alloc((size_t)N * 4);
    int*      partials = (int*)alloc(256 * 4);
    int*      poff     = (int*)alloc(256 * 4);
    int2*     csr      = (int2*)alloc((size_t)E * 8);
    _Float16* WhT      = (_Float16*)alloc(256 * 256 * 2);
    __half2*  xbuf     = (__half2*)alloc((size_t)N * NP * 4);
    __half2*  bufA     = (__half2*)alloc((size_t)N * NP * 4);
    __half2*  bufB     = (__half2*)alloc((size_t)N * NP * 4);
    (void)ws_size;

    const int NB = (N + 1023) / 1024;
    const int NH = N * NP;

    coef_k<<<1, 64, 0, stream>>>(approx, theta, cp);
    build_whT_k<<<256, 256, 0, stream>>>(Wr, Wi, WhT);
    zero_counts_k<<<(N + 255) / 256, 256, 0, stream>>>(row_cnt, N);
    hist_k<<<(E + 255) / 256, 256, 0, stream>>>(rowv, row_cnt, E);
    scan_partial_k<<<NB, 256, 0, stream>>>(row_cnt, partials, N);
    scan_toplevel_k<<<1, 64, 0, stream>>>(partials, poff, NB);
    scan_write_k<<<NB, 256, 0, stream>>>(row_cnt, poff, row_start, edge_pos, N, E);
    scatter_k<<<(E + 255) / 256, 256, 0, stream>>>(rowv, colv, ew, edge_pos, csr, E);
    convert_x_k<<<(NH + 255) / 256, 256, 0, stream>>>((const float2*)xr, (const float2*)xi, xbuf, NH);

    const int NG = (N + 3) / 4;   // 4 rows per block
    const uint2* xb4 = (const uint2*)xbuf;
    uint2* bA = (uint2*)bufA;
    uint2* bB = (uint2*)bufB;

    // step1: That1 -> bufB
    spmm_first4_k<<<NG, 256, 0, stream>>>(xb4, row_start, csr, cp, bB, acc4, N);
    // step2 (k=2): -> bufA
    spmm_step4_k<<<NG, 256, 0, stream>>>(bB, xb4, row_start, csr, cp, 2, bA, acc4, N, 1);
    // step3 (k=3): -> bufB (own-row overwrite safe)
    spmm_step4_k<<<NG, 256, 0, stream>>>(bA, bB, row_start, csr, cp, 3, bB, acc4, N, 1);
    // step4 (k=4): -> bufA
    spmm_step4_k<<<NG, 256, 0, stream>>>(bB, bA, row_start, csr, cp, 4, bA, acc4, N, 1);
    // step5 (k=5): dst not needed
    spmm_step4_k<<<NG, 256, 0, stream>>>(bA, bB, row_start, csr, cp, 5, bB, acc4, N, 0);

    gemm_silu_mfma_k<<<(N + 31) / 32, 256, 0, stream>>>(WhT, outp, N);
}

// Round 5
// 698.405 us; speedup vs baseline: 2.8580x; 1.1969x over previous
//
#include <hip/hip_runtime.h>
#include <hip/hip_fp16.h>
#include <math.h>

// FrameletLayer: Chebyshev framelet graph conv + complex linear + CSiLU.
// Scaled recurrence That_k = T_k/32^k (fp16-safe); MFMA f16 for the complex GEMM.
// CSR built via two-level bucket sort (128-row buckets) for write-dense placement.
// CSR entry = 4B {col:16 | weight:fp16}  -- assumes N <= 65536 (here N=50000).

#define CH   128
#define NP   128   // half2 lanes per row (256 half)
#define NP4  64    // half4 lanes per row
#define RPB  128   // rows per bucket
#define MAXBUCK 512

typedef _Float16 half8 __attribute__((ext_vector_type(8)));
typedef float f32x4 __attribute__((ext_vector_type(4)));

// ---------------- bucket-sort CSR build ----------------

__global__ __launch_bounds__(256) void bucket_hist_k(
        const int* __restrict__ row, int* __restrict__ bucket_cnt, int E, int nbuck) {
    __shared__ int h[MAXBUCK];
    for (int j = threadIdx.x; j < nbuck; j += 256) h[j] = 0;
    __syncthreads();
    int stride = gridDim.x * 256;
    for (int e = blockIdx.x * 256 + threadIdx.x; e < E; e += stride)
        atomicAdd(&h[row[e] >> 7], 1);
    __syncthreads();
    for (int j = threadIdx.x; j < nbuck; j += 256)
        if (h[j]) atomicAdd(&bucket_cnt[j], h[j]);
}

__global__ __launch_bounds__(512) void bucket_scan_k(
        const int* __restrict__ bucket_cnt, int* __restrict__ bucket_start,
        int* __restrict__ bucket_cursor, int nbuck, int E) {
    __shared__ int sd[MAXBUCK];
    int t = threadIdx.x;
    int v = (t < nbuck) ? bucket_cnt[t] : 0;
    sd[t] = v;
    __syncthreads();
    for (int off = 1; off < MAXBUCK; off <<= 1) {
        int y = (t >= off) ? sd[t - off] : 0;
        __syncthreads();
        sd[t] += y;
        __syncthreads();
    }
    int excl = sd[t] - v;
    if (t < nbuck) { bucket_start[t] = excl; bucket_cursor[t] = excl; }
    if (t == 0) bucket_start[nbuck] = E;
}

// tmp entry: {x = (row&127)<<16 | col, y = float_bits(w)}
__global__ __launch_bounds__(256) void bucket_place_k(
        const int* __restrict__ row, const int* __restrict__ col,
        const float* __restrict__ w, int* __restrict__ bucket_cursor,
        uint2* __restrict__ tmp, int E, int chunk, int nbuck) {
    __shared__ int cnt[MAXBUCK];
    __shared__ int cur[MAXBUCK];
    int e0 = blockIdx.x * chunk;
    int e1 = e0 + chunk; if (e1 > E) e1 = E;
    if (e0 >= E) return;
    for (int j = threadIdx.x; j < nbuck; j += 256) cnt[j] = 0;
    __syncthreads();
    for (int e = e0 + threadIdx.x; e < e1; e += 256)
        atomicAdd(&cnt[row[e] >> 7], 1);
    __syncthreads();
    for (int j = threadIdx.x; j < nbuck; j += 256) {
        int c = cnt[j];
        cur[j] = c ? atomicAdd(&bucket_cursor[j], c) : 0;
    }
    __syncthreads();
    for (int e = e0 + threadIdx.x; e < e1; e += 256) {
        int r = row[e];
        int b = r >> 7;
        int p = atomicAdd(&cur[b], 1);
        uint2 ent;
        ent.x = ((unsigned)(r & (RPB - 1)) << 16) | (unsigned)col[e];
        ent.y = __float_as_uint(w[e]);
        tmp[p] = ent;
    }
}

// one block per bucket: row hist + scan -> row_start; place 4B CSR entries
__global__ __launch_bounds__(256) void csr_build_k(
        const uint2* __restrict__ tmp, const int* __restrict__ bucket_start,
        int* __restrict__ row_start, unsigned* __restrict__ csr4,
        int N, int E, int nbuck) {
    __shared__ int hist[RPB];
    __shared__ int sc[RPB];
    __shared__ int curs[RPB];
    int b = blockIdx.x;
    int t = threadIdx.x;
    int base = bucket_start[b];
    int endp = bucket_start[b + 1];
    if (t < RPB) hist[t] = 0;
    __syncthreads();
    for (int e = base + t; e < endp; e += 256)
        atomicAdd(&hist[tmp[e].x >> 16], 1);
    __syncthreads();
    if (t < RPB) sc[t] = hist[t];
    __syncthreads();
    for (int off = 1; off < RPB; off <<= 1) {
        int y = 0;
        if (t < RPB && t >= off) y = sc[t - off];
        __syncthreads();
        if (t < RPB) sc[t] += y;
        __syncthreads();
    }
    int r0 = b << 7;
    if (t < RPB) {
        int excl = sc[t] - hist[t];
        if (r0 + t < N) row_start[r0 + t] = base + excl;
        curs[t] = base + excl;
    }
    if (b == nbuck - 1 && t == 0) row_start[N] = E;
    __syncthreads();
    for (int e = base + t; e < endp; e += 256) {
        uint2 ent = tmp[e];
        int rl = ent.x >> 16;
        unsigned c = ent.x & 0xffffu;
        float wv = __uint_as_float(ent.y) * (-1.0f / 16.0f);   // B/16 entries
        int p = atomicAdd(&curs[rl], 1);
        __half hw = __float2half(wv);
        csr4[p] = (c << 16) | (unsigned)__half_as_ushort(hw);
    }
}

// cp[k] = (sum_f theta[f]*approx[f][k]) * 32^k
__global__ void coef_k(const float* __restrict__ approx, const float* __restrict__ theta,
                       float* cp) {
    int k = threadIdx.x;
    if (k < 6 && blockIdx.x == 0) {
        float s = 0.f;
        for (int f = 0; f < 4; f++) s += theta[f] * approx[f * 6 + k];
        float sc = 1.f;
        for (int j = 0; j < k; j++) sc *= 32.f;
        cp[k] = s * sc;
    }
}

// x (fp32 xr,xi) -> fused fp16 [N][128 half2]: p<64 real pair, p>=64 imag pair
__global__ void convert_x_k(const float2* __restrict__ xr2, const float2* __restrict__ xi2,
                            __half2* __restrict__ xbuf, int total) {
    int idx = blockIdx.x * blockDim.x + threadIdx.x;
    if (idx >= total) return;
    int i = idx >> 7;
    int p = idx & 127;
    float2 v = (p < 64) ? xr2[(size_t)i * 64 + p] : xi2[(size_t)i * 64 + (p - 64)];
    xbuf[idx] = __floats2half2_rn(v.x, v.y);
}

// WhT[j*256+k] = Wbig[k][j]; Wbig = [[Wr^T, Wi^T],[-Wi^T, Wr^T]] (k = input dim)
__global__ void build_whT_k(const float* __restrict__ Wr, const float* __restrict__ Wi,
                            _Float16* __restrict__ WhT) {
    int idx = blockIdx.x * 256 + threadIdx.x;
    int j = idx >> 8, k = idx & 255;
    float v;
    if (j < 128) {
        v = (k < 128) ? Wr[j * 128 + k] : -Wi[j * 128 + (k - 128)];
    } else {
        v = (k < 128) ? Wi[(j - 128) * 128 + k] : Wr[(j - 128) * 128 + (k - 128)];
    }
    WhT[idx] = (_Float16)v;
}

// ---------------- SpMM steps (half4 gather, 4 rows/block, 64 lanes/row) ----------------

__device__ __forceinline__ void unpack4(uint2 v, float& a, float& b, float& c, float& d) {
    __half2 lo = *reinterpret_cast<__half2*>(&v.x);
    __half2 hi = *reinterpret_cast<__half2*>(&v.y);
    float2 f0 = __half22float2(lo);
    float2 f1 = __half22float2(hi);
    a = f0.x; b = f0.y; c = f1.x; d = f1.y;
}

__device__ __forceinline__ void decode(unsigned ent, int& c, float& wv) {
    c = (int)(ent >> 16);
    wv = __half2float(__ushort_as_half((unsigned short)(ent & 0xffffu)));
}

// s[0..3] += sum_e w_e * src[col_e][p4]; 4-edge groups, one group prefetched ahead
__device__ __forceinline__ void gather_row(
        const uint2* __restrict__ src, const unsigned* __restrict__ csr,
        int beg, int end, int p4,
        float& s0, float& s1, float& s2, float& s3) {
    int e = beg;
    unsigned c0, c1, c2, c3;
    if (e + 4 <= end) { c0 = csr[e]; c1 = csr[e+1]; c2 = csr[e+2]; c3 = csr[e+3]; }
    for (; e + 8 <= end; e += 4) {
        unsigned n0 = csr[e+4], n1 = csr[e+5], n2 = csr[e+6], n3 = csr[e+7];
        int ia, ib, ic, id; float wa, wb, wc, wd;
        decode(c0, ia, wa); decode(c1, ib, wb); decode(c2, ic, wc); decode(c3, id, wd);
        float a0,a1,a2,a3, b0,b1,b2,b3, d0,d1,d2,d3, f0,f1,f2,f3;
        unpack4(src[(size_t)ia * NP4 + p4], a0,a1,a2,a3);
        unpack4(src[(size_t)ib * NP4 + p4], b0,b1,b2,b3);
        unpack4(src[(size_t)ic * NP4 + p4], d0,d1,d2,d3);
        unpack4(src[(size_t)id * NP4 + p4], f0,f1,f2,f3);
        s0 += wa*a0 + wb*b0 + wc*d0 + wd*f0;
        s1 += wa*a1 + wb*b1 + wc*d1 + wd*f1;
        s2 += wa*a2 + wb*b2 + wc*d2 + wd*f2;
        s3 += wa*a3 + wb*b3 + wc*d3 + wd*f3;
        c0 = n0; c1 = n1; c2 = n2; c3 = n3;
    }
    if (e + 4 <= end) {
        int ia, ib, ic, id; float wa, wb, wc, wd;
        decode(c0, ia, wa); decode(c1, ib, wb); decode(c2, ic, wc); decode(c3, id, wd);
        float a0,a1,a2,a3, b0,b1,b2,b3, d0,d1,d2,d3, f0,f1,f2,f3;
        unpack4(src[(size_t)ia * NP4 + p4], a0,a1,a2,a3);
        unpack4(src[(size_t)ib * NP4 + p4], b0,b1,b2,b3);
        unpack4(src[(size_t)ic * NP4 + p4], d0,d1,d2,d3);
        unpack4(src[(size_t)id * NP4 + p4], f0,f1,f2,f3);
        s0 += wa*a0 + wb*b0 + wc*d0 + wd*f0;
        s1 += wa*a1 + wb*b1 + wc*d1 + wd*f1;
        s2 += wa*a2 + wb*b2 + wc*d2 + wd*f2;
        s3 += wa*a3 + wb*b3 + wc*d3 + wd*f3;
        e += 4;
    }
    for (; e < end; e++) {
        int ia; float wa;
        decode(csr[e], ia, wa);
        float a0,a1,a2,a3;
        unpack4(src[(size_t)ia * NP4 + p4], a0,a1,a2,a3);
        s0 += wa*a0; s1 += wa*a1; s2 += wa*a2; s3 += wa*a3;
    }
}

// That1 = (B/32) x ; acc = cp0*x + cp1*That1
__global__ __launch_bounds__(256) void spmm_first4_k(
        const uint2* __restrict__ xb4,
        const int* __restrict__ row_start, const unsigned* __restrict__ csr,
        const float* __restrict__ cp,
        uint2* __restrict__ t1, float4* __restrict__ acc4, int N) {
    int t = threadIdx.x;
    int rl = t >> 6;
    int p4 = t & 63;
    int i = blockIdx.x * 4 + rl;
    if (i >= N) return;
    int beg = row_start[i], end = row_start[i + 1];
    float s0 = 0.f, s1 = 0.f, s2 = 0.f, s3 = 0.f;
    gather_row(xb4, csr, beg, end, p4, s0, s1, s2, s3);
    s0 *= 0.5f; s1 *= 0.5f; s2 *= 0.5f; s3 *= 0.5f;   // B/16 -> B/32
    uint2 pk;
    __half2 h0 = __floats2half2_rn(s0, s1);
    __half2 h1 = __floats2half2_rn(s2, s3);
    pk.x = *reinterpret_cast<unsigned*>(&h0);
    pk.y = *reinterpret_cast<unsigned*>(&h1);
    t1[(size_t)i * NP4 + p4] = pk;
    float o0,o1,o2,o3;
    unpack4(xb4[(size_t)i * NP4 + p4], o0,o1,o2,o3);
    float cp0 = cp[0], cp1 = cp[1];
    int half = p4 >> 5, q = p4 & 31;
    float4 a;
    a.x = cp0 * o0 + cp1 * s0;
    a.y = cp0 * o1 + cp1 * s1;
    a.z = cp0 * o2 + cp1 * s2;
    a.w = cp0 * o3 + cp1 * s3;
    acc4[(size_t)half * N * 32 + (size_t)i * 32 + q] = a;
}

// That_k = (B/16)*cur - prev/1024 ; acc += cp[k]*That_k ; optional dst write
__global__ __launch_bounds__(256) void spmm_step4_k(
        const uint2* __restrict__ cur, const uint2* __restrict__ prev,
        const int* __restrict__ row_start, const unsigned* __restrict__ csr,
        const float* __restrict__ cp, int k,
        uint2* __restrict__ dst, float4* __restrict__ acc4, int N, int writeDst) {
    int t = threadIdx.x;
    int rl = t >> 6;
    int p4 = t & 63;
    int i = blockIdx.x * 4 + rl;
    if (i >= N) return;
    int beg = row_start[i], end = row_start[i + 1];
    float s0 = 0.f, s1 = 0.f, s2 = 0.f, s3 = 0.f;
    gather_row(cur, csr, beg, end, p4, s0, s1, s2, s3);
    float p0,p1,p2,p3;
    unpack4(prev[(size_t)i * NP4 + p4], p0,p1,p2,p3);
    const float inv = 1.0f / 1024.0f;
    float t0 = s0 - inv * p0;
    float t1v = s1 - inv * p1;
    float t2v = s2 - inv * p2;
    float t3v = s3 - inv * p3;
    if (writeDst) {
        uint2 pk;
        __half2 h0 = __floats2half2_rn(t0, t1v);
        __half2 h1 = __floats2half2_rn(t2v, t3v);
        pk.x = *reinterpret_cast<unsigned*>(&h0);
        pk.y = *reinterpret_cast<unsigned*>(&h1);
        dst[(size_t)i * NP4 + p4] = pk;
    }
    float ck = cp[k];
    int half = p4 >> 5, q = p4 & 31;
    size_t aidx = (size_t)half * N * 32 + (size_t)i * 32 + q;
    float4 a = acc4[aidx];
    a.x += ck * t0;
    a.y += ck * t1v;
    a.z += ck * t2v;
    a.w += ck * t3v;
    acc4[aidx] = a;
}

// ---------------- MFMA complex GEMM + SiLU (in-place over acc in d_out) ----------------
__global__ __launch_bounds__(256) void gemm_silu_mfma_k(
        const _Float16* __restrict__ WhT,   // [j][k] = Wbig[k][j], 256x256
        float* __restrict__ out, int N) {
    __shared__ _Float16 U[32][264];
    int t = threadIdx.x;
    int row0 = blockIdx.x * 32;
    const float4* out4 = (const float4*)out;
    const float isc = 1.0f / 32.0f;
    for (int q = t; q < 2048; q += 256) {
        int r = q >> 6;
        int kq = q & 63;
        int row = row0 + r;
        float4 v = make_float4(0.f, 0.f, 0.f, 0.f);
        if (row < N) {
            int half = kq >> 5;
            v = out4[(size_t)half * N * 32 + (size_t)row * 32 + (kq & 31)];
        }
        int k = kq * 4;
        U[r][k]   = (_Float16)(v.x * isc);
        U[r][k+1] = (_Float16)(v.y * isc);
        U[r][k+2] = (_Float16)(v.z * isc);
        U[r][k+3] = (_Float16)(v.w * isc);
    }
    __syncthreads();

    int wave = t >> 6;
    int lane = t & 63;
    int colbase = wave * 64;
    int lr = lane & 15;
    int lg = lane >> 4;
    f32x4 acc[2][4] = {};
    for (int kb = 0; kb < 8; kb++) {
        int k0 = kb * 32 + lg * 8;
        half8 a0 = *(const half8*)&U[lr][k0];
        half8 a1 = *(const half8*)&U[16 + lr][k0];
        #pragma unroll
        for (int nf = 0; nf < 4; nf++) {
            int col = colbase + nf * 16 + lr;
            half8 b = *(const half8*)&WhT[(size_t)col * 256 + k0];
            acc[0][nf] = __builtin_amdgcn_mfma_f32_16x16x32_f16(a0, b, acc[0][nf], 0, 0, 0);
            acc[1][nf] = __builtin_amdgcn_mfma_f32_16x16x32_f16(a1, b, acc[1][nf], 0, 0, 0);
        }
    }

    #pragma unroll
    for (int mf = 0; mf < 2; mf++) {
        #pragma unroll
        for (int nf = 0; nf < 4; nf++) {
            int col = colbase + nf * 16 + lr;
            int half = col >> 7, j = col & 127;
            #pragma unroll
            for (int r4 = 0; r4 < 4; r4++) {
                int row = row0 + mf * 16 + lg * 4 + r4;
                if (row < N) {
                    float v = acc[mf][nf][r4] * 32.f;
                    float sv = v / (1.f + expf(-v));
                    out[(size_t)half * N * CH + (size_t)row * CH + j] = sv;
                }
            }
        }
    }
}

// ---------------- launch ----------------

extern "C" void kernel_launch(void* const* d_in, const int* in_sizes, int n_in,
                              void* d_out, int out_size, void* d_ws, size_t ws_size,
                              hipStream_t stream) {
    const float* xr     = (const float*)d_in[0];
    const float* xi     = (const float*)d_in[1];
    const int*   eidx   = (const int*)d_in[2];
    const float* ew     = (const float*)d_in[3];
    const float* approx = (const float*)d_in[4];
    const float* theta  = (const float*)d_in[5];
    const float* Wr     = (const float*)d_in[6];
    const float* Wi     = (const float*)d_in[7];

    const int N = in_sizes[0] / CH;
    const int E = in_sizes[3];
    const int* rowv = eidx;
    const int* colv = eidx + E;

    float*  outp = (float*)d_out;
    float4* acc4 = (float4*)d_out;

    char* w8 = (char*)d_ws;
    size_t off = 0;
    auto alloc = [&](size_t bytes) -> void* {
        void* ptr = w8 + off;
        off += (bytes + 255) & ~(size_t)255;
        return ptr;
    };
    float*    cp        = (float*)alloc(64 * 4);
    int*      bucket_cnt= (int*)alloc(MAXBUCK * 4);
    int*      bucket_st = (int*)alloc((MAXBUCK + 1) * 4);
    int*      bucket_cur= (int*)alloc(MAXBUCK * 4);
    int*      row_start = (int*)alloc((size_t)(N + 1) * 4);
    unsigned* csr4      = (unsigned*)alloc((size_t)E * 4);
    uint2*    tmp       = (uint2*)alloc((size_t)E * 8);
    _Float16* WhT       = (_Float16*)alloc(256 * 256 * 2);
    __half2*  xbuf      = (__half2*)alloc((size_t)N * NP * 4);
    __half2*  bufA      = (__half2*)alloc((size_t)N * NP * 4);
    __half2*  bufB      = (__half2*)alloc((size_t)N * NP * 4);
    (void)ws_size;

    const int NH = N * NP;
    const int nbuck = (N + RPB - 1) / RPB;
    const int chunk = (E + 255) / 256;

    hipMemsetAsync(bucket_cnt, 0, (size_t)MAXBUCK * 4, stream);
    coef_k<<<1, 64, 0, stream>>>(approx, theta, cp);
    build_whT_k<<<256, 256, 0, stream>>>(Wr, Wi, WhT);
    bucket_hist_k<<<256, 256, 0, stream>>>(rowv, bucket_cnt, E, nbuck);
    bucket_scan_k<<<1, MAXBUCK, 0, stream>>>(bucket_cnt, bucket_st, bucket_cur, nbuck, E);
    bucket_place_k<<<256, 256, 0, stream>>>(rowv, colv, ew, bucket_cur, tmp, E, chunk, nbuck);
    csr_build_k<<<nbuck, 256, 0, stream>>>(tmp, bucket_st, row_start, csr4, N, E, nbuck);
    convert_x_k<<<(NH + 255) / 256, 256, 0, stream>>>((const float2*)xr, (const float2*)xi, xbuf, NH);

    const int NG = (N + 3) / 4;   // 4 rows per block
    const uint2* xb4 = (const uint2*)xbuf;
    uint2* bA = (uint2*)bufA;
    uint2* bB = (uint2*)bufB;

    // step1: That1 -> bufB
    spmm_first4_k<<<NG, 256, 0, stream>>>(xb4, row_start, csr4, cp, bB, acc4, N);
    // step2 (k=2): -> bufA
    spmm_step4_k<<<NG, 256, 0, stream>>>(bB, xb4, row_start, csr4, cp, 2, bA, acc4, N, 1);
    // step3 (k=3): -> bufB (own-row overwrite safe)
    spmm_step4_k<<<NG, 256, 0, stream>>>(bA, bB, row_start, csr4, cp, 3, bB, acc4, N, 1);
    // step4 (k=4): -> bufA
    spmm_step4_k<<<NG, 256, 0, stream>>>(bB, bA, row_start, csr4, cp, 4, bA, acc4, N, 1);
    // step5 (k=5): dst not needed
    spmm_step4_k<<<NG, 256, 0, stream>>>(bA, bB, row_start, csr4, cp, 5, bB, acc4, N, 0);

    gemm_silu_mfma_k<<<(N + 31) / 32, 256, 0, stream>>>(WhT, outp, N);
}